// Round 12
// baseline (298.811 us; speedup 1.0000x reference)
//
#include <hip/hip_runtime.h>

#define B_ 32
#define N_ 10000
#define D_ 256
#define HA_ 500
#define HM_ 1024
#define NCHUNK_ 157        // n-chunks of 64
#define NBLK46_ 314        // 157 chunks x 2 batch-halves (16 b each)

// -------- ws layout (floats) --------
// 0      th      8192   tanh(feature@W_pf + b_pf)   [b][d]
// 8192   gf      8192   relu(relu(ehr@W1+b1)@W2+b2) [b][d]
// 16384  S       32     (memset to 0; k46 atomics)
// 16416  c0      1
// 16448  w_eff   256
// 16704  gate    8192
// 24896  hwT     8192   ([d][b])
// 33088  partial 1286144 ([c=314][b16=16][d=256])
// total ~5.3 MB (ws_size = 256 MiB per fill counter)

// kfused: 65 blocks. r<32: per-b {state->th, t1, gf, gate}; r in [32,64): w_eff; r==64: c0.
// No atomics anywhere -> only S needs memset.
__global__ __launch_bounds__(256) void kfused(
    const float* __restrict__ ehr, const float* __restrict__ path,
    const float* __restrict__ W_pf, const float* __restrict__ b_pf,
    const float* __restrict__ W1, const float* __restrict__ b1,
    const float* __restrict__ W2, const float* __restrict__ b2,
    const float* __restrict__ W_gate, const float* __restrict__ b_gate,
    const float* __restrict__ W_s1, const float* __restrict__ b_s1,
    const float* __restrict__ W_s2, const float* __restrict__ b_s2,
    float* __restrict__ th, float* __restrict__ gf, float* __restrict__ gate,
    float* __restrict__ w_eff, float* __restrict__ c0)
{
  int r = blockIdx.x, tid = threadIdx.x;
  if (r < 32) {
    __shared__ float es[256];     // ehr[b]
    __shared__ float fs[1536];    // 6-segment feature (concat order: path,ehr,e*p,e-p,p-e,e+p)
    __shared__ float ts1[1024];   // relu(ehr@W1+b1)
    int b = r;
    float ev = ehr[b * D_ + tid], pv = path[b * D_ + tid];
    es[tid] = ev;
    fs[tid]        = pv;
    fs[256 + tid]  = ev;
    fs[512 + tid]  = ev * pv;
    fs[768 + tid]  = ev - pv;
    fs[1024 + tid] = pv - ev;
    fs[1280 + tid] = ev + pv;
    __syncthreads();

    // th = tanh(feature @ W_pf + b_pf)
    {
      float acc = b_pf[tid];
      #pragma unroll 8
      for (int k = 0; k < 1536; ++k) acc += fs[k] * W_pf[k * D_ + tid];
      th[b * D_ + tid] = tanhf(acc);
    }
    // t1 = relu(ehr @ W1 + b1) -> LDS
    #pragma unroll
    for (int jc = 0; jc < 4; ++jc) {
      int j = jc * 256 + tid;
      float a = b1[j];
      #pragma unroll 8
      for (int d = 0; d < 256; ++d) a += es[d] * W1[d * HM_ + j];
      ts1[j] = fmaxf(a, 0.f);
    }
    __syncthreads();
    // gf = relu(t1 @ W2 + b2)
    {
      float a = b2[tid];
      #pragma unroll 8
      for (int i = 0; i < 1024; ++i) a += ts1[i] * W2[i * D_ + tid];
      gf[b * D_ + tid] = fmaxf(a, 0.f);
    }
    // gate = sigmoid(ehr @ W_gate + b_gate)
    {
      float a = b_gate[tid];
      #pragma unroll 8
      for (int d = 0; d < 256; ++d) a += es[d] * W_gate[d * D_ + tid];
      gate[b * D_ + tid] = 1.f / (1.f + __expf(-a));
    }
  } else if (r < 64) {
    // w_eff[d] = sum_k W_s1[d,k]*W_s2[k]; 8 d per block, 32 lanes per d
    int dc = r - 32;
    int g = tid >> 5, lk = tid & 31;
    int d = dc * 8 + g;
    float sum = 0.f;
    for (int k = lk; k < HA_; k += 32) sum += W_s1[d * HA_ + k] * W_s2[k];
    #pragma unroll
    for (int off = 16; off > 0; off >>= 1) sum += __shfl_down(sum, off, 32);
    if (lk == 0) w_eff[d] = sum;
  } else {
    // c0 = sum_k b_s1[k]*W_s2[k] + b_s2
    float v = b_s1[tid] * W_s2[tid];
    int k2i = tid + 256;
    if (k2i < HA_) v += b_s1[k2i] * W_s2[k2i];
    __shared__ float rb[256];
    rb[tid] = v;
    __syncthreads();
    for (int sft = 128; sft > 0; sft >>= 1) {
      if (tid < sft) rb[tid] += rb[tid + sft];
      __syncthreads();
    }
    if (tid == 0) c0[0] = rb[0] + b_s2[0];
  }
}

// k46: fused e-compute + brother-partial. 314 blocks = 157 n-chunks x 2 b-halves.
// Per block: 16 b x 64 n (2 sub-tiles of 32); e stays in LDS; partial register-accumulated.
__global__ __launch_bounds__(256, 2) void k46(
    const float* __restrict__ emb, const float* __restrict__ th,
    const float* __restrict__ w_eff, const float* __restrict__ c0,
    const float* __restrict__ action_space,
    float* __restrict__ partial, float* __restrict__ S)
{
  __shared__ float embs[32 * 256];   // swizzled emb sub-tile
  __shared__ float us[16 * 256];     // u[b16][d] = th*w_eff
  __shared__ float e_lds[16][36];
  int tid = threadIdx.x;
  int blk = blockIdx.x;
  int chunk = blk >> 1, bh = blk & 1;
  const float4* emb4 = (const float4*)emb;

  // prologue: u = th * w_eff for this half's 16 b (no tanh here)
  for (int j = tid; j < 4096; j += 256) {
    int bb = j >> 8, d = j & 255;
    us[j] = th[(bh * 16 + bb) * 256 + d] * w_eff[d];
  }
  float c0v = c0[0];

  int dq = tid & 63, bg2 = tid >> 6;           // phase-B mapping: 4 groups x 4 b
  int d0 = dq << 2, b02 = bg2 << 2;
  float acc[4][4] = {};
  float sloc = 0.f;

  for (int st = 0; st < 2; ++st) {
    int n0 = chunk * 64 + st * 32;
    __syncthreads();   // us (st=0) / previous phase-B reads (st=1) complete
    for (int t = tid; t < 2048; t += 256) {
      int rr = t >> 6, c4 = t & 63;
      int nr = n0 + rr; if (nr >= N_) nr = N_ - 1;
      float4 v = emb4[nr * 64 + c4];
      *(float4*)&embs[rr * 256 + ((c4 << 2) ^ ((rr & 7) << 2))] = v;
    }
    __syncthreads();

    // phase A: e for 2 b's per thread (8 bgroups x 2 b = 16 b; 32 n-lanes)
    {
      int nl = tid & 31, bg = tid >> 5;
      int b0 = bg * 2;
      const float* es = embs + nl * 256;
      const float* up = us + b0 * 256;
      int sw = (nl & 7) << 2;
      float a0 = 0.f, a1 = 0.f;
      #pragma unroll 8
      for (int d4 = 0; d4 < 256; d4 += 4) {
        float4 ev = *(const float4*)&es[d4 ^ sw];
        float4 u0 = *(const float4*)&up[d4];
        float4 u1 = *(const float4*)&up[256 + d4];
        a0 += ev.x * u0.x + ev.y * u0.y + ev.z * u0.z + ev.w * u0.w;
        a1 += ev.x * u1.x + ev.y * u1.y + ev.z * u1.z + ev.w * u1.w;
      }
      int n = n0 + nl;
      float e0 = 0.f, e1 = 0.f;
      if (n < N_) {
        int gb = bh * 16 + b0;
        e0 = __expf((a0 + c0v) * action_space[(gb + 0) * N_ + n]);
        e1 = __expf((a1 + c0v) * action_space[(gb + 1) * N_ + n]);
      }
      e_lds[b0 + 0][nl] = e0;
      e_lds[b0 + 1][nl] = e1;
    }
    __syncthreads();

    // S partials (local accumulate; one atomic per b at end)
    if (tid < 16) {
      float s = 0.f;
      #pragma unroll 8
      for (int j = 0; j < 32; ++j) s += e_lds[tid][j];
      sloc += s;
    }

    // phase B: acc[j][] += sum_nn e[b02+j,nn] * emb[nn, d0..d0+3]
    #pragma unroll 4
    for (int nn = 0; nn < 32; ++nn) {
      float4 ev = *(const float4*)&embs[nn * 256 + (d0 ^ ((nn & 7) << 2))];
      #pragma unroll
      for (int j = 0; j < 4; ++j) {
        float pv = e_lds[b02 + j][nn];            // wave-uniform address -> broadcast
        acc[j][0] += ev.x * pv;
        acc[j][1] += ev.y * pv;
        acc[j][2] += ev.z * pv;
        acc[j][3] += ev.w * pv;
      }
    }
  }

  if (tid < 16) atomicAdd(&S[bh * 16 + tid], sloc);
  float* pb = partial + blk * 4096;
  #pragma unroll
  for (int j = 0; j < 4; ++j) {
    *(float4*)&pb[(b02 + j) * 256 + d0] =
        make_float4(acc[j][0], acc[j][1], acc[j][2], acc[j][3]);
  }
}

// kred: brother = sum_c partial; highway epilogue -> hwT.
__global__ __launch_bounds__(256) void kred(
    const float* __restrict__ partial, const float* __restrict__ S,
    const float* __restrict__ th, const float* __restrict__ gate,
    const float* __restrict__ ehr, float* __restrict__ hwT)
{
  int blk = blockIdx.x;
  int o0 = blk * 32;
  int t = threadIdx.x;
  int lo = t & 31, g = t >> 5;
  int oo = o0 + lo;
  int b = oo >> 8, d = oo & 255;
  int bh = b >> 4, b16 = b & 15;
  float sum = 0.f;
  #pragma unroll 4
  for (int ch = g; ch < NCHUNK_; ch += 8)
    sum += partial[(ch * 2 + bh) * 4096 + b16 * 256 + d];
  __shared__ float red[8][33];
  red[g][lo] = sum;
  __syncthreads();
  if (t < 32) {
    float bp = 0.f;
    #pragma unroll
    for (int gg = 0; gg < 8; ++gg) bp += red[gg][t];
    int o = o0 + t;
    int bb = o >> 8, dd = o & 255;
    float br = th[o] * bp / S[bb];
    float gv = gate[o];
    float hw = br * (1.f - gv) + ehr[o] * gv;
    hwT[dd * B_ + bb] = hw;
  }
}

// k7: out = 0.2*sig(hw.Wlay+b_lay)*as + 0.8*sig(gf.Wgl+b_gl)*lm
// 640 blocks x 256; 79 n-tiles x 8 b-splits of 4; 4-wave d-split + LDS combine; XCD co-location.
__global__ __launch_bounds__(256) void k7(
    const float* __restrict__ hwT, const float* __restrict__ gf,
    const float* __restrict__ W_lay, const float* __restrict__ b_lay,
    const float* __restrict__ W_gl, const float* __restrict__ b_gl,
    const float* __restrict__ action_space, const float* __restrict__ level_mask,
    float* __restrict__ out)
{
  int blk = blockIdx.x;
  int xcd = blk & 7, slot = blk >> 3;
  int nt = xcd * 10 + (slot >> 3);
  int bs = slot & 7;
  if (nt >= 79) return;
  int tid = threadIdx.x;
  int wave = tid >> 6, lane = tid & 63;
  int n0 = nt * 128;
  int b0 = bs * 4;

  __shared__ float4 hs[256], gs[256];
  hs[tid] = *(const float4*)&hwT[tid * B_ + b0];
  {
    float4 gq;
    gq.x = gf[(b0 + 0) * D_ + tid];
    gq.y = gf[(b0 + 1) * D_ + tid];
    gq.z = gf[(b0 + 2) * D_ + tid];
    gq.w = gf[(b0 + 3) * D_ + tid];
    gs[tid] = gq;
  }
  __syncthreads();

  int nn = n0 + 2 * lane;
  int nc = (nn < N_) ? nn : 0;
  const float* Wl = W_lay + nc;
  const float* Wg = W_gl + nc;
  int dbase = wave * 64;
  float accL[2][4] = {}, accG[2][4] = {};
  #pragma unroll 8
  for (int dd = 0; dd < 64; ++dd) {
    int d = dbase + dd;
    float2 wl = *(const float2*)&Wl[(size_t)d * N_];
    float2 wg = *(const float2*)&Wg[(size_t)d * N_];
    float4 h = hs[d];
    float4 g = gs[d];
    accL[0][0] += wl.x * h.x; accL[0][1] += wl.x * h.y;
    accL[0][2] += wl.x * h.z; accL[0][3] += wl.x * h.w;
    accL[1][0] += wl.y * h.x; accL[1][1] += wl.y * h.y;
    accL[1][2] += wl.y * h.z; accL[1][3] += wl.y * h.w;
    accG[0][0] += wg.x * g.x; accG[0][1] += wg.x * g.y;
    accG[0][2] += wg.x * g.z; accG[0][3] += wg.x * g.w;
    accG[1][0] += wg.y * g.x; accG[1][1] += wg.y * g.y;
    accG[1][2] += wg.y * g.z; accG[1][3] += wg.y * g.w;
  }

  __shared__ float comb[3][64][16];
  if (wave > 0) {
    float* c = &comb[wave - 1][lane][0];
    #pragma unroll
    for (int jn = 0; jn < 2; ++jn)
      #pragma unroll
      for (int jb = 0; jb < 4; ++jb) {
        c[jn * 4 + jb] = accL[jn][jb];
        c[8 + jn * 4 + jb] = accG[jn][jb];
      }
  }
  __syncthreads();
  if (wave == 0) {
    #pragma unroll
    for (int w = 0; w < 3; ++w) {
      const float* c = &comb[w][lane][0];
      #pragma unroll
      for (int jn = 0; jn < 2; ++jn)
        #pragma unroll
        for (int jb = 0; jb < 4; ++jb) {
          accL[jn][jb] += c[jn * 4 + jb];
          accG[jn][jb] += c[8 + jn * 4 + jb];
        }
    }
    #pragma unroll
    for (int jn = 0; jn < 2; ++jn) {
      int n = nn + jn;
      if (n < N_) {
        float bl = b_lay[n], bgv = b_gl[n], lm = level_mask[n];
        #pragma unroll
        for (int jb = 0; jb < 4; ++jb) {
          int b = b0 + jb;
          float as = action_space[b * N_ + n];
          float sl = 1.f / (1.f + __expf(-(accL[jn][jb] + bl)));
          float sg = 1.f / (1.f + __expf(-(accG[jn][jb] + bgv)));
          out[b * N_ + n] = 0.2f * sl * as + 0.8f * sg * lm;
        }
      }
    }
  }
}

extern "C" void kernel_launch(void* const* d_in, const int* in_sizes, int n_in,
                              void* d_out, int out_size, void* d_ws, size_t ws_size,
                              hipStream_t stream) {
  const float* ehr    = (const float*)d_in[0];
  const float* path   = (const float*)d_in[1];
  const float* aspace = (const float*)d_in[2];
  const float* lmask  = (const float*)d_in[3];
  const float* emb    = (const float*)d_in[4];
  const float* W_pf   = (const float*)d_in[5];
  const float* b_pf   = (const float*)d_in[6];
  const float* W_s1   = (const float*)d_in[7];
  const float* b_s1   = (const float*)d_in[8];
  const float* W_s2   = (const float*)d_in[9];
  const float* b_s2   = (const float*)d_in[10];
  const float* W_gate = (const float*)d_in[11];
  const float* b_gate = (const float*)d_in[12];
  const float* W1     = (const float*)d_in[13];
  const float* b1     = (const float*)d_in[14];
  const float* W2     = (const float*)d_in[15];
  const float* b2     = (const float*)d_in[16];
  const float* W_gl   = (const float*)d_in[17];
  const float* b_gl   = (const float*)d_in[18];
  const float* W_lay  = (const float*)d_in[19];
  const float* b_lay  = (const float*)d_in[20];
  float* out = (float*)d_out;
  float* ws = (float*)d_ws;

  float* th     = ws;
  float* gf     = ws + 8192;
  float* S      = ws + 16384;
  float* c0     = ws + 16416;
  float* w_eff  = ws + 16448;
  float* gate   = ws + 16704;
  float* hwT    = ws + 24896;
  float* partial= ws + 33088;   // 314*4096 floats

  hipMemsetAsync(S, 0, 32 * sizeof(float), stream);   // only S needs zeroing (k46 atomics)
  kfused<<<65, 256, 0, stream>>>(ehr, path, W_pf, b_pf, W1, b1, W2, b2, W_gate, b_gate,
                                 W_s1, b_s1, W_s2, b_s2, th, gf, gate, w_eff, c0);
  k46<<<NBLK46_, 256, 0, stream>>>(emb, th, w_eff, c0, aspace, partial, S);
  kred<<<256, 256, 0, stream>>>(partial, S, th, gate, ehr, hwT);
  k7<<<640, 256, 0, stream>>>(hwT, gf, W_lay, b_lay, W_gl, b_gl, aspace, lmask, out);
}

// Round 13
// 178.963 us; speedup vs baseline: 1.6697x; 1.6697x over previous
//
#include <hip/hip_runtime.h>

#define B_ 32
#define N_ 10000
#define D_ 256
#define HA_ 500
#define HM_ 1024
#define NCHUNK_ 157        // n-chunks of 64
#define NBLK46_ 314        // 157 chunks x 2 batch-halves (16 b each)

// Round-11 configuration (measured 186.6 us) restored after kfused regression (298.8 us,
// occupancy 1.5% latency chain). Small-M GEMMs need many blocks + short per-thread chains.

__global__ __launch_bounds__(256) void k1(
    const float* __restrict__ ehr, const float* __restrict__ path,
    const float* __restrict__ W_pf, const float* __restrict__ W1, const float* __restrict__ b1,
    const float* __restrict__ W_gate, const float* __restrict__ b_gate,
    const float* __restrict__ W_s1, const float* __restrict__ b_s1, const float* __restrict__ W_s2,
    const float* __restrict__ b_s2,
    float* __restrict__ state_pre, float* __restrict__ t1, float* __restrict__ gate,
    float* __restrict__ w_eff, float* __restrict__ c0)
{
  int r = blockIdx.x, tid = threadIdx.x;
  if (r < 384) {
    // state_pre partials: (b, segment s, k-half kh)
    int b = r / 12, rem = r % 12, s = rem >> 1, kh = rem & 1;
    __shared__ float fs[256];
    float ev = ehr[b * D_ + tid], pv = path[b * D_ + tid];
    float f;
    switch (s) {
      case 0: f = pv; break;
      case 1: f = ev; break;
      case 2: f = ev * pv; break;
      case 3: f = ev - pv; break;
      case 4: f = pv - ev; break;
      default: f = ev + pv; break;
    }
    fs[tid] = f;
    __syncthreads();
    const float* wp = W_pf + s * 256 * D_ + tid;
    int dd0 = kh * 128;
    float acc = 0.f;
    #pragma unroll 8
    for (int dd = dd0; dd < dd0 + 128; ++dd) acc += fs[dd] * wp[dd * D_];
    atomicAdd(&state_pre[b * D_ + tid], acc);
  } else if (r < 512) {
    int idx = r - 384, b = idx >> 2, jc = idx & 3, j = jc * 256 + tid;
    __shared__ float es[256];
    es[tid] = ehr[b * D_ + tid];
    __syncthreads();
    const float* w = W1 + j;
    float acc = b1[j];
    #pragma unroll 8
    for (int d = 0; d < 256; ++d) acc += es[d] * w[d * HM_];
    t1[b * HM_ + j] = fmaxf(acc, 0.f);
  } else if (r < 544) {
    int b = r - 512;
    __shared__ float es[256];
    es[tid] = ehr[b * D_ + tid];
    __syncthreads();
    const float* w = W_gate + tid;
    float acc = b_gate[tid];
    #pragma unroll 8
    for (int d = 0; d < 256; ++d) acc += es[d] * w[d * D_];
    gate[b * D_ + tid] = 1.f / (1.f + __expf(-acc));
  } else if (r < 576) {
    int dc = r - 544;
    int g = tid >> 5, lk = tid & 31;
    int d = dc * 8 + g;
    float sum = 0.f;
    for (int k = lk; k < HA_; k += 32) sum += W_s1[d * HA_ + k] * W_s2[k];
    #pragma unroll
    for (int off = 16; off > 0; off >>= 1) sum += __shfl_down(sum, off, 32);
    if (lk == 0) w_eff[d] = sum;
  } else {
    float v = b_s1[tid] * W_s2[tid];
    int k2i = tid + 256;
    if (k2i < HA_) v += b_s1[k2i] * W_s2[k2i];
    __shared__ float rb[256];
    rb[tid] = v;
    __syncthreads();
    for (int sft = 128; sft > 0; sft >>= 1) {
      if (tid < sft) rb[tid] += rb[tid + sft];
      __syncthreads();
    }
    if (tid == 0) c0[0] = rb[0] + b_s2[0];
  }
}

// gf_pre partials: 256 blocks = 32 b x 8 i-chunks of 128
__global__ __launch_bounds__(256) void k2(
    const float* __restrict__ t1, const float* __restrict__ W2, float* __restrict__ gf_pre)
{
  int b = blockIdx.x >> 3, ih = blockIdx.x & 7, tid = threadIdx.x;
  __shared__ float ts[128];
  if (tid < 128) ts[tid] = t1[b * HM_ + ih * 128 + tid];
  __syncthreads();
  const float* w = W2 + (ih * 128) * D_ + tid;
  float acc = 0.f;
  #pragma unroll 8
  for (int i = 0; i < 128; ++i) acc += ts[i] * w[i * D_];
  atomicAdd(&gf_pre[b * D_ + tid], acc);
}

// k46: fused u-compute + e-compute + brother-partial. 314 blocks = 157 n-chunks x 2 b-halves.
__global__ __launch_bounds__(256, 2) void k46(
    const float* __restrict__ emb, const float* __restrict__ state_pre,
    const float* __restrict__ b_pf, const float* __restrict__ w_eff,
    const float* __restrict__ c0, const float* __restrict__ action_space,
    float* __restrict__ partial, float* __restrict__ S)
{
  __shared__ float embs[32 * 256];   // swizzled emb sub-tile
  __shared__ float us[16 * 256];     // u[b16][d], computed in-kernel
  __shared__ float e_lds[16][36];
  int tid = threadIdx.x;
  int blk = blockIdx.x;
  int chunk = blk >> 1, bh = blk & 1;
  const float4* emb4 = (const float4*)emb;

  // prologue: u = tanh(state_pre + b_pf) * w_eff for this half's 16 b
  for (int j = tid; j < 4096; j += 256) {
    int bb = j >> 8, d = j & 255;
    us[j] = tanhf(state_pre[(bh * 16 + bb) * 256 + d] + b_pf[d]) * w_eff[d];
  }
  float c0v = c0[0];

  int dq = tid & 63, bg2 = tid >> 6;           // phase-B mapping: 4 groups x 4 b
  int d0 = dq << 2, b02 = bg2 << 2;
  float acc[4][4] = {};
  float sloc = 0.f;

  for (int st = 0; st < 2; ++st) {
    int n0 = chunk * 64 + st * 32;
    __syncthreads();   // us (st=0) / previous phase-B reads (st=1) complete
    for (int t = tid; t < 2048; t += 256) {
      int rr = t >> 6, c4 = t & 63;
      int nr = n0 + rr; if (nr >= N_) nr = N_ - 1;
      float4 v = emb4[nr * 64 + c4];
      *(float4*)&embs[rr * 256 + ((c4 << 2) ^ ((rr & 7) << 2))] = v;
    }
    __syncthreads();

    // phase A: e for 2 b's per thread (8 bgroups x 2 b = 16 b; 32 n-lanes)
    {
      int nl = tid & 31, bg = tid >> 5;
      int b0 = bg * 2;
      const float* es = embs + nl * 256;
      const float* up = us + b0 * 256;
      int sw = (nl & 7) << 2;
      float a0 = 0.f, a1 = 0.f;
      #pragma unroll 8
      for (int d4 = 0; d4 < 256; d4 += 4) {
        float4 ev = *(const float4*)&es[d4 ^ sw];
        float4 u0 = *(const float4*)&up[d4];
        float4 u1 = *(const float4*)&up[256 + d4];
        a0 += ev.x * u0.x + ev.y * u0.y + ev.z * u0.z + ev.w * u0.w;
        a1 += ev.x * u1.x + ev.y * u1.y + ev.z * u1.z + ev.w * u1.w;
      }
      int n = n0 + nl;
      float e0 = 0.f, e1 = 0.f;
      if (n < N_) {
        int gb = bh * 16 + b0;
        e0 = __expf((a0 + c0v) * action_space[(gb + 0) * N_ + n]);
        e1 = __expf((a1 + c0v) * action_space[(gb + 1) * N_ + n]);
      }
      e_lds[b0 + 0][nl] = e0;
      e_lds[b0 + 1][nl] = e1;
    }
    __syncthreads();

    // S partials (local accumulate; one atomic per b at end)
    if (tid < 16) {
      float s = 0.f;
      #pragma unroll 8
      for (int j = 0; j < 32; ++j) s += e_lds[tid][j];
      sloc += s;
    }

    // phase B: acc[j][] += sum_nn e[b02+j,nn] * emb[nn, d0..d0+3]
    #pragma unroll 4
    for (int nn = 0; nn < 32; ++nn) {
      float4 ev = *(const float4*)&embs[nn * 256 + (d0 ^ ((nn & 7) << 2))];
      #pragma unroll
      for (int j = 0; j < 4; ++j) {
        float pv = e_lds[b02 + j][nn];            // wave-uniform address -> broadcast
        acc[j][0] += ev.x * pv;
        acc[j][1] += ev.y * pv;
        acc[j][2] += ev.z * pv;
        acc[j][3] += ev.w * pv;
      }
    }
  }

  if (tid < 16) atomicAdd(&S[bh * 16 + tid], sloc);
  float* pb = partial + blk * 4096;
  #pragma unroll
  for (int j = 0; j < 4; ++j) {
    *(float4*)&pb[(b02 + j) * 256 + d0] =
        make_float4(acc[j][0], acc[j][1], acc[j][2], acc[j][3]);
  }
}

// kred: brother = sum_c partial; highway epilogue (recomputes state) -> hwT.
__global__ __launch_bounds__(256) void kred(
    const float* __restrict__ partial, const float* __restrict__ S,
    const float* __restrict__ state_pre, const float* __restrict__ b_pf,
    const float* __restrict__ gate, const float* __restrict__ ehr, float* __restrict__ hwT)
{
  int blk = blockIdx.x;
  int o0 = blk * 32;
  int t = threadIdx.x;
  int lo = t & 31, g = t >> 5;
  int oo = o0 + lo;
  int b = oo >> 8, d = oo & 255;
  int bh = b >> 4, b16 = b & 15;
  float sum = 0.f;
  #pragma unroll 4
  for (int ch = g; ch < NCHUNK_; ch += 8)
    sum += partial[(ch * 2 + bh) * 4096 + b16 * 256 + d];
  __shared__ float red[8][33];
  red[g][lo] = sum;
  __syncthreads();
  if (t < 32) {
    float bp = 0.f;
    #pragma unroll
    for (int gg = 0; gg < 8; ++gg) bp += red[gg][t];
    int o = o0 + t;
    int bb = o >> 8, dd = o & 255;
    float st = tanhf(state_pre[o] + b_pf[dd]);
    float br = st * bp / S[bb];
    float gv = gate[o];
    float hw = br * (1.f - gv) + ehr[o] * gv;
    hwT[dd * B_ + bb] = hw;
  }
}

// k7: out = 0.2*sig(hw.Wlay+b_lay)*as + 0.8*sig(relu(gf_pre+b2).Wgl+b_gl)*lm
__global__ __launch_bounds__(256) void k7(
    const float* __restrict__ hwT, const float* __restrict__ gf_pre,
    const float* __restrict__ b2,
    const float* __restrict__ W_lay, const float* __restrict__ b_lay,
    const float* __restrict__ W_gl, const float* __restrict__ b_gl,
    const float* __restrict__ action_space, const float* __restrict__ level_mask,
    float* __restrict__ out)
{
  int blk = blockIdx.x;
  int xcd = blk & 7, slot = blk >> 3;
  int nt = xcd * 10 + (slot >> 3);
  int bs = slot & 7;
  if (nt >= 79) return;
  int tid = threadIdx.x;
  int wave = tid >> 6, lane = tid & 63;
  int n0 = nt * 128;
  int b0 = bs * 4;

  __shared__ float4 hs[256], gs[256];
  hs[tid] = *(const float4*)&hwT[tid * B_ + b0];
  {
    float b2v = b2[tid];
    float4 gq;
    gq.x = fmaxf(gf_pre[(b0 + 0) * D_ + tid] + b2v, 0.f);
    gq.y = fmaxf(gf_pre[(b0 + 1) * D_ + tid] + b2v, 0.f);
    gq.z = fmaxf(gf_pre[(b0 + 2) * D_ + tid] + b2v, 0.f);
    gq.w = fmaxf(gf_pre[(b0 + 3) * D_ + tid] + b2v, 0.f);
    gs[tid] = gq;
  }
  __syncthreads();

  int nn = n0 + 2 * lane;
  int nc = (nn < N_) ? nn : 0;
  const float* Wl = W_lay + nc;
  const float* Wg = W_gl + nc;
  int dbase = wave * 64;
  float accL[2][4] = {}, accG[2][4] = {};
  #pragma unroll 8
  for (int dd = 0; dd < 64; ++dd) {
    int d = dbase + dd;
    float2 wl = *(const float2*)&Wl[(size_t)d * N_];
    float2 wg = *(const float2*)&Wg[(size_t)d * N_];
    float4 h = hs[d];
    float4 g = gs[d];
    accL[0][0] += wl.x * h.x; accL[0][1] += wl.x * h.y;
    accL[0][2] += wl.x * h.z; accL[0][3] += wl.x * h.w;
    accL[1][0] += wl.y * h.x; accL[1][1] += wl.y * h.y;
    accL[1][2] += wl.y * h.z; accL[1][3] += wl.y * h.w;
    accG[0][0] += wg.x * g.x; accG[0][1] += wg.x * g.y;
    accG[0][2] += wg.x * g.z; accG[0][3] += wg.x * g.w;
    accG[1][0] += wg.y * g.x; accG[1][1] += wg.y * g.y;
    accG[1][2] += wg.y * g.z; accG[1][3] += wg.y * g.w;
  }

  __shared__ float comb[3][64][16];
  if (wave > 0) {
    float* c = &comb[wave - 1][lane][0];
    #pragma unroll
    for (int jn = 0; jn < 2; ++jn)
      #pragma unroll
      for (int jb = 0; jb < 4; ++jb) {
        c[jn * 4 + jb] = accL[jn][jb];
        c[8 + jn * 4 + jb] = accG[jn][jb];
      }
  }
  __syncthreads();
  if (wave == 0) {
    #pragma unroll
    for (int w = 0; w < 3; ++w) {
      const float* c = &comb[w][lane][0];
      #pragma unroll
      for (int jn = 0; jn < 2; ++jn)
        #pragma unroll
        for (int jb = 0; jb < 4; ++jb) {
          accL[jn][jb] += c[jn * 4 + jb];
          accG[jn][jb] += c[8 + jn * 4 + jb];
        }
    }
    #pragma unroll
    for (int jn = 0; jn < 2; ++jn) {
      int n = nn + jn;
      if (n < N_) {
        float bl = b_lay[n], bgv = b_gl[n], lm = level_mask[n];
        #pragma unroll
        for (int jb = 0; jb < 4; ++jb) {
          int b = b0 + jb;
          float as = action_space[b * N_ + n];
          float sl = 1.f / (1.f + __expf(-(accL[jn][jb] + bl)));
          float sg = 1.f / (1.f + __expf(-(accG[jn][jb] + bgv)));
          out[b * N_ + n] = 0.2f * sl * as + 0.8f * sg * lm;
        }
      }
    }
  }
}

extern "C" void kernel_launch(void* const* d_in, const int* in_sizes, int n_in,
                              void* d_out, int out_size, void* d_ws, size_t ws_size,
                              hipStream_t stream) {
  const float* ehr    = (const float*)d_in[0];
  const float* path   = (const float*)d_in[1];
  const float* aspace = (const float*)d_in[2];
  const float* lmask  = (const float*)d_in[3];
  const float* emb    = (const float*)d_in[4];
  const float* W_pf   = (const float*)d_in[5];
  const float* b_pf   = (const float*)d_in[6];
  const float* W_s1   = (const float*)d_in[7];
  const float* b_s1   = (const float*)d_in[8];
  const float* W_s2   = (const float*)d_in[9];
  const float* b_s2   = (const float*)d_in[10];
  const float* W_gate = (const float*)d_in[11];
  const float* b_gate = (const float*)d_in[12];
  const float* W1     = (const float*)d_in[13];
  const float* b1     = (const float*)d_in[14];
  const float* W2     = (const float*)d_in[15];
  const float* b2     = (const float*)d_in[16];
  const float* W_gl   = (const float*)d_in[17];
  const float* b_gl   = (const float*)d_in[18];
  const float* W_lay  = (const float*)d_in[19];
  const float* b_lay  = (const float*)d_in[20];
  float* out = (float*)d_out;
  float* ws = (float*)d_ws;

  float* state_pre = ws;
  float* gf_pre    = ws + 8192;
  float* S         = ws + 16384;
  float* c0        = ws + 16416;
  float* w_eff     = ws + 16448;
  float* gate      = ws + 16704;
  float* t1        = ws + 24896;
  float* hwT       = ws + 57664;
  float* partial   = ws + 65856;   // 314*4096 floats

  hipMemsetAsync(d_ws, 0, 16417 * sizeof(float), stream);
  k1<<<577, 256, 0, stream>>>(ehr, path, W_pf, W1, b1, W_gate, b_gate, W_s1, b_s1, W_s2, b_s2,
                              state_pre, t1, gate, w_eff, c0);
  k2<<<256, 256, 0, stream>>>(t1, W2, gf_pre);
  k46<<<NBLK46_, 256, 0, stream>>>(emb, state_pre, b_pf, w_eff, c0, aspace, partial, S);
  kred<<<256, 256, 0, stream>>>(partial, S, state_pre, b_pf, gate, ehr, hwT);
  k7<<<640, 256, 0, stream>>>(hwT, gf_pre, b2, W_lay, b_lay, W_gl, b_gl, aspace, lmask, out);
}